// Round 1
// 323.392 us; speedup vs baseline: 1.1998x; 1.1998x over previous
//
#include <hip/hip_runtime.h>
#include <hip/hip_bf16.h>

// Problem constants. Harness: fp32 inputs, fp32 output buffer.
constexpr int BB = 2;
constexpr int SS = 2048;
constexpr int EMBED = 2048;
constexpr int NH = 32;
constexpr int NKV = 8;
constexpr int HD = 64;
constexpr int WIN = 128;
constexpr int M_ROWS = BB * SS;           // 4096
constexpr int QKVC = 3072;                // packed qkv columns
constexpr float SCALE = 0.125f;

typedef __bf16 bf16x8 __attribute__((ext_vector_type(8)));
typedef float f32x4 __attribute__((ext_vector_type(4)));

__device__ inline uint4 cvt8(float4 lo, float4 hi) {
    union { __hip_bfloat16 h[8]; uint4 u; } r;
    r.h[0] = __hip_bfloat16(lo.x); r.h[1] = __hip_bfloat16(lo.y);
    r.h[2] = __hip_bfloat16(lo.z); r.h[3] = __hip_bfloat16(lo.w);
    r.h[4] = __hip_bfloat16(hi.x); r.h[5] = __hip_bfloat16(hi.y);
    r.h[6] = __hip_bfloat16(hi.z); r.h[7] = __hip_bfloat16(hi.w);
    return r.u;
}
__device__ inline uint4 load8(const float* p) {
    float4 lo = *(const float4*)p;
    float4 hi = *(const float4*)(p + 4);
    return cvt8(lo, hi);
}

// async global->LDS, 16B per lane (wave-uniform base + lane*16).
__device__ inline void gload_lds16(const __hip_bfloat16* g, uint4* l) {
    __builtin_amdgcn_global_load_lds(
        (const __attribute__((address_space(1))) void*)g,
        (__attribute__((address_space(3))) void*)l, 16, 0, 0);
}

// ---------------------------------------------------------------------------
// prep: convert x -> xb and pack wq|wk|wv -> wqkv (bf16). 2048 elems/block.
// ---------------------------------------------------------------------------
__global__ __launch_bounds__(256) void prep_cvt(
    const float* __restrict__ x,  const float* __restrict__ wq,
    const float* __restrict__ wk, const float* __restrict__ wv,
    __hip_bfloat16* __restrict__ xb, __hip_bfloat16* __restrict__ wqkv)
{
    long bid = blockIdx.x;
    const float* src; __hip_bfloat16* dst; long off;
    if (bid < 4096)      { src = x;  dst = xb;             off = bid * 2048; }
    else if (bid < 6144) { src = wq; dst = wqkv;           off = (bid - 4096) * 2048; }
    else if (bid < 6656) { src = wk; dst = wqkv + 4194304; off = (bid - 6144) * 2048; }
    else                 { src = wv; dst = wqkv + 5242880; off = (bid - 6656) * 2048; }
    long i = off + (long)threadIdx.x * 8;
    *(uint4*)(dst + i) = load8(src + i);
}

__global__ __launch_bounds__(256) void cvt_bf16(
    const float* __restrict__ in, __hip_bfloat16* __restrict__ out, long n)
{
    long i = ((long)blockIdx.x * 256 + threadIdx.x) * 8;
    if (i + 8 <= n) *(uint4*)(out + i) = load8(in + i);
}

// ---------------------------------------------------------------------------
// 256x256 8-phase GEMM (T3+T4+T5, plain-HIP port of the m201 schedule).
// C[M][N] = A[M][K] · B[N][K]^T, bf16 in, TC out. 512 threads = 8 waves
// (2M x 4N), per-wave output 128x64. BK=64 split into two [256][32]
// ks-sub-buffers (row stride 64B -> frag ds_read_b128 is naturally
// bank-balanced: bank group (row&1)*16 + quad*4, 8 lanes/group = free).
// LDS 128KB: 2 bufs x {A ks0, A ks1, B ks0, B ks1} x 16KB.
// Counted vmcnt: 2 loads/phase; sub-buffer staged at (t,p) first read at
// t+1 -> vmcnt(4) before end-barrier of phases 1 and 3 releases exactly
// the 4 loads the next phase-pair needs, keeps 4 in flight (never 0).
// K % 128 == 0 required (K-loop unrolled x2 so buffer index is literal).
// ---------------------------------------------------------------------------
#define BAR() __builtin_amdgcn_s_barrier()
#define LGKM0() do { \
    asm volatile("s_waitcnt lgkmcnt(0)" ::: "memory"); \
    __builtin_amdgcn_sched_barrier(0); } while (0)
#define VMC4() asm volatile("s_waitcnt vmcnt(4)" ::: "memory")

#define STAGE(NB, AB, KS, P0, P1, KOFF) do { \
    __hip_bfloat16* _d = &lds[(NB) * 32768 + (AB) * 16384 + (KS) * 8192 + t * 8]; \
    gload_lds16((P0) + (KOFF), (uint4*)_d); \
    gload_lds16((P1) + (KOFF), (uint4*)(_d + 4096)); \
} while (0)

#define LOAD_A(CB, MI0, KS) \
    _Pragma("unroll") for (int mi = 0; mi < 4; ++mi) \
        af[mi] = *(const bf16x8*)&lds[(CB) + (KS) * 8192 + aoff + ((MI0) + mi) * 512];

#define LOAD_B(CB, KS) \
    _Pragma("unroll") for (int ni = 0; ni < 4; ++ni) \
        bfr[ni] = *(const bf16x8*)&lds[(CB) + 16384 + (KS) * 8192 + boff + ni * 512];

#define MFMA_HALF(MI0) \
    _Pragma("unroll") for (int mi = 0; mi < 4; ++mi) { \
        _Pragma("unroll") for (int ni = 0; ni < 4; ++ni) \
            acc[(MI0) + mi][ni] = __builtin_amdgcn_mfma_f32_16x16x32_bf16( \
                af[mi], bfr[ni], acc[(MI0) + mi][ni], 0, 0, 0); \
    }

#define KTILE(CUR, KT) do { \
    const long kn = (long)(((KT) + 1 < nkt) ? ((KT) + 1) : (KT)) << 6; \
    constexpr int cb = (CUR) * 32768; \
    constexpr int nb = (CUR) ^ 1; \
    /* phase 0: ks0, mi 0-3 */ \
    LOAD_B(cb, 0); LOAD_A(cb, 0, 0); \
    STAGE(nb, 0, 0, pa0, pa1, kn); \
    BAR(); LGKM0(); \
    __builtin_amdgcn_s_setprio(1); MFMA_HALF(0); __builtin_amdgcn_s_setprio(0); \
    BAR(); \
    /* phase 1: ks0, mi 4-7 */ \
    LOAD_A(cb, 4, 0); \
    STAGE(nb, 1, 0, pb0, pb1, kn); \
    BAR(); LGKM0(); \
    __builtin_amdgcn_s_setprio(1); MFMA_HALF(4); __builtin_amdgcn_s_setprio(0); \
    VMC4(); \
    BAR(); \
    /* phase 2: ks1, mi 0-3 */ \
    LOAD_B(cb, 1); LOAD_A(cb, 0, 1); \
    STAGE(nb, 0, 1, pa0, pa1, kn + 32); \
    BAR(); LGKM0(); \
    __builtin_amdgcn_s_setprio(1); MFMA_HALF(0); __builtin_amdgcn_s_setprio(0); \
    BAR(); \
    /* phase 3: ks1, mi 4-7 */ \
    LOAD_A(cb, 4, 1); \
    STAGE(nb, 1, 1, pb0, pb1, kn + 32); \
    BAR(); LGKM0(); \
    __builtin_amdgcn_s_setprio(1); MFMA_HALF(4); __builtin_amdgcn_s_setprio(0); \
    VMC4(); \
    BAR(); \
} while (0)

template <typename TC>
__global__ __launch_bounds__(512) void gemm256(
    const __hip_bfloat16* __restrict__ A,
    const __hip_bfloat16* __restrict__ Bm,
    TC* __restrict__ C, int K, int ldc, int nbx)
{
    __shared__ __hip_bfloat16 lds[65536];   // 128 KiB

    const int t = threadIdx.x;
    const int lane = t & 63;
    const int wid = t >> 6;
    const int wm = wid >> 2;                // 0..1
    const int wn = wid & 3;                 // 0..3
    const int lrow = lane & 15;
    const int quad = lane >> 4;

    // bijective XCD swizzle (nwg % 8 == 0 for both call sites)
    int bid = blockIdx.x;
    const int nwg = gridDim.x;
    if ((nwg & 7) == 0) bid = (bid & 7) * (nwg >> 3) + (bid >> 3);
    const long blockM = (long)(bid / nbx) * 256;
    const long blockN = (long)(bid % nbx) * 256;

    // staging: load l covers rows l*128 + (t>>2), 16B slot t&3; dest linear t*16B
    const int srow = t >> 2;
    const int sslot = (t & 3) * 8;
    const __hip_bfloat16* pa0 = A  + (blockM + srow) * (long)K + sslot;
    const __hip_bfloat16* pa1 = A  + (blockM + 128 + srow) * (long)K + sslot;
    const __hip_bfloat16* pb0 = Bm + (blockN + srow) * (long)K + sslot;
    const __hip_bfloat16* pb1 = Bm + (blockN + 128 + srow) * (long)K + sslot;

    // frag read offsets (elems) inside a [256][32] sub-buffer
    const int aoff = (wm * 128 + lrow) * 32 + quad * 8;
    const int boff = (wn * 64 + lrow) * 32 + quad * 8;

    // prologue: stage all 4 sub-buffers of tile 0 into buf 0, drain once
    STAGE(0, 0, 0, pa0, pa1, 0);
    STAGE(0, 1, 0, pb0, pb1, 0);
    STAGE(0, 0, 1, pa0, pa1, 32);
    STAGE(0, 1, 1, pb0, pb1, 32);
    asm volatile("s_waitcnt vmcnt(0)" ::: "memory");
    BAR();

    f32x4 acc[8][4] = {};
    bf16x8 af[4], bfr[4];
    const int nkt = K >> 6;

    for (int kt = 0; kt < nkt; kt += 2) {
        KTILE(0, kt);
        KTILE(1, kt + 1);
    }

    asm volatile("s_waitcnt vmcnt(0)" ::: "memory");

    #pragma unroll
    for (int mi = 0; mi < 8; ++mi)
        #pragma unroll
        for (int ni = 0; ni < 4; ++ni)
            #pragma unroll
            for (int r = 0; r < 4; ++r) {
                long rr = blockM + wm * 128 + mi * 16 + quad * 4 + r;
                long cc = blockN + wn * 64 + ni * 16 + lrow;
                C[rr * (long)ldc + cc] = TC(acc[mi][ni][r]);
            }
}

// ---------------------------------------------------------------------------
// Per-head RMSNorm + RoPE, in place on packed qkv[row][3072].
// ---------------------------------------------------------------------------
__global__ __launch_bounds__(256) void norm_rope(
    __hip_bfloat16* __restrict__ qkv,
    const float* __restrict__ qw,
    const float* __restrict__ kw)
{
    const int QROWS = M_ROWS * NH;      // 131072
    int gid = blockIdx.x * 4 + (threadIdx.x >> 6);
    int lane = threadIdx.x & 63;

    __hip_bfloat16* base;
    const float* wptr;
    int s;
    if (gid < QROWS) {
        int row = gid >> 5;             // /NH
        base = qkv + (long)row * QKVC + (gid & 31) * HD;
        s = row % SS;
        wptr = qw;
    } else {
        int g = gid - QROWS;
        int row = g >> 3;               // /NKV
        base = qkv + (long)row * QKVC + 2048 + (g & 7) * HD;
        s = row % SS;
        wptr = kw;
    }

    float x = (float)base[lane];
    float ss = x * x;
    for (int off = 32; off; off >>= 1) ss += __shfl_xor(ss, off);
    float scale = rsqrtf(ss * (1.0f / 64.0f) + 1e-6f);
    float xn = x * scale * wptr[lane];

    float partner = __shfl_xor(xn, 32);
    int i = lane & 31;
    float ang = (float)s * powf(10000.0f, -(float)i * (1.0f / 32.0f));
    float sn, cs;
    sincosf(ang, &sn, &cs);
    float y = (lane < 32) ? (xn * cs - partner * sn) : (xn * cs + partner * sn);
    base[lane] = __hip_bfloat16(y);
}

// ---------------------------------------------------------------------------
// MFMA sliding-window attention with sink, reading packed qkv[row][3072].
// ---------------------------------------------------------------------------
constexpr int SPAN = 192;
constexpr int KROW = 72;
constexpr int PROW = 200;

__global__ __launch_bounds__(256) void attn_mfma(
    const __hip_bfloat16* __restrict__ qkv,
    const int* __restrict__ amask,
    const float* __restrict__ sinks,
    __hip_bfloat16* __restrict__ ao)     // [4096][2048] (b,s,h,d)
{
    __shared__ __hip_bfloat16 KsPs[SPAN * KROW];
    __shared__ __hip_bfloat16 Vt[64 * PROW];

    const int bid = blockIdx.x;
    const int qt = bid & 31;
    const int h = (bid >> 5) & 31;
    const int b = bid >> 10;
    const int kv = h >> 2;
    const int q0 = qt * 64;
    const int base = q0 - (WIN - 1);
    const int t = threadIdx.x;
    const int w = t >> 6;
    const int lane = t & 63;
    const int lrow = lane & 15;
    const int quad = lane >> 4;

    for (int c = t; c < SPAN * 8; c += 256) {
        int j = c >> 3;
        int d0 = (c & 7) * 8;
        int kg = base + j;
        uint4 kk = {0, 0, 0, 0}, vv = {0, 0, 0, 0};
        if (kg >= 0 && kg < SS) {
            long rowoff = ((long)b * SS + kg) * QKVC + kv * HD + d0;
            kk = *(const uint4*)(qkv + rowoff + 2048);
            vv = *(const uint4*)(qkv + rowoff + 2560);
        }
        *(uint4*)&KsPs[j * KROW + d0] = kk;
        const __hip_bfloat16* vp = (const __hip_bfloat16*)&vv;
        #pragma unroll
        for (int u = 0; u < 8; u++) Vt[(d0 + u) * PROW + j] = vp[u];
    }
    __syncthreads();

    const __hip_bfloat16* qrow =
        qkv + ((long)b * SS + q0 + w * 16 + lrow) * QKVC + h * HD;
    bf16x8 qa0 = *(const bf16x8*)(qrow + quad * 8);
    bf16x8 qa1 = *(const bf16x8*)(qrow + 32 + quad * 8);

    f32x4 s[12] = {};
    #pragma unroll
    for (int ni = 0; ni < 12; ni++) {
        bf16x8 kb0 = *(const bf16x8*)&KsPs[(ni * 16 + lrow) * KROW + quad * 8];
        bf16x8 kb1 = *(const bf16x8*)&KsPs[(ni * 16 + lrow) * KROW + 32 + quad * 8];
        s[ni] = __builtin_amdgcn_mfma_f32_16x16x32_bf16(qa0, kb0, s[ni], 0, 0, 0);
        s[ni] = __builtin_amdgcn_mfma_f32_16x16x32_bf16(qa1, kb1, s[ni], 0, 0, 0);
    }

    bool jok[12];
    #pragma unroll
    for (int ni = 0; ni < 12; ni++) {
        int kg = base + ni * 16 + lrow;
        jok[ni] = (kg >= 0) && (kg < SS) && (amask[b * SS + (kg >= 0 && kg < SS ? kg : 0)] > 0);
    }

    const float sinkv = sinks[h];

    #pragma unroll
    for (int reg = 0; reg < 4; reg++) {
        int row = w * 16 + quad * 4 + reg;
        float mrow = -3.0e30f;
        #pragma unroll
        for (int ni = 0; ni < 12; ni++) {
            int j = ni * 16 + lrow;
            bool valid = jok[ni] && (j >= row) && (j <= row + 127);
            float val = valid ? s[ni][reg] * SCALE : -1.0e30f;
            s[ni][reg] = val;
            mrow = fmaxf(mrow, val);
        }
        #pragma unroll
        for (int off = 1; off < 16; off <<= 1) mrow = fmaxf(mrow, __shfl_xor(mrow, off));
        mrow = fmaxf(mrow, sinkv);
        float sum = 0.f;
        #pragma unroll
        for (int ni = 0; ni < 12; ni++) {
            float e = __expf(s[ni][reg] - mrow);
            s[ni][reg] = e;
            sum += e;
        }
        #pragma unroll
        for (int off = 1; off < 16; off <<= 1) sum += __shfl_xor(sum, off);
        sum += __expf(sinkv - mrow);
        float inv = 1.0f / sum;
        #pragma unroll
        for (int ni = 0; ni < 12; ni++) s[ni][reg] *= inv;
    }

    __syncthreads();

    #pragma unroll
    for (int ni = 0; ni < 12; ni++)
        #pragma unroll
        for (int reg = 0; reg < 4; reg++)
            KsPs[(w * 16 + quad * 4 + reg) * PROW + ni * 16 + lrow] =
                __hip_bfloat16(s[ni][reg]);
    __syncthreads();

    f32x4 o[4] = {};
    #pragma unroll
    for (int ks = 0; ks < 6; ks++) {
        bf16x8 pa = *(const bf16x8*)&KsPs[(w * 16 + lrow) * PROW + ks * 32 + quad * 8];
        #pragma unroll
        for (int ni = 0; ni < 4; ni++) {
            bf16x8 vb = *(const bf16x8*)&Vt[(ni * 16 + lrow) * PROW + ks * 32 + quad * 8];
            o[ni] = __builtin_amdgcn_mfma_f32_16x16x32_bf16(pa, vb, o[ni], 0, 0, 0);
        }
    }

    #pragma unroll
    for (int ni = 0; ni < 4; ni++)
        #pragma unroll
        for (int reg = 0; reg < 4; reg++) {
            int row = w * 16 + quad * 4 + reg;
            ao[((long)b * SS + q0 + row) * (NH * HD) + h * HD + ni * 16 + lrow] =
                __hip_bfloat16(o[ni][reg]);
        }
}

// ---------------------------------------------------------------------------
// Scratch plan (harness restores d_in before every launch):
//   d_out (33.5MB): xb[0:16.8M) wqkv[16.8:29.4M)   -- dead before final GEMM
//   x region (33.5MB): qkv[0:25.2M) wob[25.2:33.5M) -- x dead after prep
//   wq region (16.8MB): abuf (attn output)          -- wq dead after prep
// Order: prep -> wo-cvt -> qkv-gemm -> norm -> attn -> final gemm.
// ---------------------------------------------------------------------------
extern "C" void kernel_launch(void* const* d_in, const int* in_sizes, int n_in,
                              void* d_out, int out_size, void* d_ws, size_t ws_size,
                              hipStream_t stream) {
    const float* x     = (const float*)d_in[0];
    const int*   am    = (const int*)d_in[1];
    const float* wq    = (const float*)d_in[2];
    const float* wk    = (const float*)d_in[3];
    const float* wv    = (const float*)d_in[4];
    const float* wo    = (const float*)d_in[5];
    const float* qnw   = (const float*)d_in[6];
    const float* knw   = (const float*)d_in[7];
    const float* sinks = (const float*)d_in[8];
    float* out = (float*)d_out;

    __hip_bfloat16* xb    = (__hip_bfloat16*)d_out;
    __hip_bfloat16* wqkv  = (__hip_bfloat16*)((char*)d_out + 16777216);
    __hip_bfloat16* qkv   = (__hip_bfloat16*)x;
    __hip_bfloat16* wob   = (__hip_bfloat16*)((char*)x + 25165824);
    __hip_bfloat16* abuf  = (__hip_bfloat16*)wq;

    const long NW = (long)EMBED * EMBED;   // 4194304

    // 1. convert x + pack wq|wk|wv (7168 blocks)
    prep_cvt<<<7168, 256, 0, stream>>>(x, wq, wk, wv, xb, wqkv);
    // 2. convert wo into dead x tail
    cvt_bf16<<<NW / 2048, 256, 0, stream>>>(wo, wob, NW);

    // 3. fused QKV projection: qkv[4096][3072], 16x12 = 192 blocks
    gemm256<__hip_bfloat16><<<192, 512, 0, stream>>>(
        xb, wqkv, qkv, EMBED, QKVC, QKVC / 256);

    // 4. RMSNorm + RoPE on q,k inside packed qkv
    int rows = M_ROWS * NH + M_ROWS * NKV;   // 163840
    norm_rope<<<rows / 4, 256, 0, stream>>>(qkv, qnw, knw);

    // 5. attention -> abuf [4096][2048]
    attn_mfma<<<BB * NH * (SS / 64), 256, 0, stream>>>(qkv, am, sinks, abuf);

    // 6. output projection: fp32 into d_out, 16x8 = 128 blocks
    gemm256<float><<<128, 512, 0, stream>>>(
        abuf, wob, out, EMBED, EMBED, EMBED / 256);
}